// Round 8
// baseline (149.916 us; speedup 1.0000x reference)
//
#include <hip/hip_runtime.h>
#include <hip/hip_bf16.h>

__device__ __forceinline__ float sigm(float x) { return 1.0f / (1.0f + __expf(-x)); }

// Workspace float layout (all written by frap_setup every launch):
#define WS_WCM   0      // [2][20][20] = 800   w_comb * relu(yc) per mask value
#define WS_YA    800    // [60][20]            w_feat[:, :16] . X[key]  (+ b_feat/4)
#define WS_YB    2000   // [60][20]            w_feat[:, 16:] . X[key]  (+ b_feat/4)
#define WS_BCOMB 3200   // 20
#define WS_WFIN  3220   // 20
#define WS_BFIN  3240   // 1

// ---------------- setup: tiny, 1 block. Computes all derived tables. --------
__global__ __launch_bounds__(256) void frap_setup(
    const float* __restrict__ emb_phase, const float* __restrict__ w_veh,
    const float* __restrict__ b_veh,     const float* __restrict__ w_line,
    const float* __restrict__ b_line,    const float* __restrict__ emb_const,
    const float* __restrict__ w_feat,    const float* __restrict__ b_feat,
    const float* __restrict__ w_const,   const float* __restrict__ b_const,
    const float* __restrict__ w_comb,    const float* __restrict__ b_comb,
    const float* __restrict__ w_final,   const float* __restrict__ b_final,
    float* __restrict__ ws)
{
    __shared__ float s_stage[820];   // [0,128)=w_line [128,768)=w_feat [768,784)=b_line
                                     // [784,788)=w_veh [788,792)=b_veh [792,800)=emb_phase [800,820)=b_feat
    const int tid = threadIdx.x;
    for (int k = tid; k < 128; k += 256) s_stage[k] = w_line[k];
    for (int k = tid; k < 640; k += 256) s_stage[128 + k] = w_feat[k];
    if (tid < 16)                s_stage[768 + tid] = b_line[tid];
    if (tid < 4)                 s_stage[784 + tid] = w_veh[tid];
    if (tid >= 4 && tid < 8)     s_stage[784 + tid] = b_veh[tid - 4];
    if (tid >= 8 && tid < 16)    s_stage[784 + tid] = emb_phase[tid - 8];
    if (tid >= 16 && tid < 36)   s_stage[784 + tid] = b_feat[tid - 16];
    __syncthreads();

    // YA/YB: 240 threads, 4 per key (5 outputs each)
    if (tid < 240) {
        int key = tid >> 2, part = tid & 3;
        int veh = key >> 1, pb = key & 1;
        float vf = (float)veh;
        float line[8];
#pragma unroll
        for (int k = 0; k < 4; k++) line[k] = sigm(fmaf(vf, s_stage[784 + k], s_stage[788 + k]));
#pragma unroll
        for (int k = 0; k < 4; k++) line[4 + k] = sigm(s_stage[792 + pb * 4 + k]);
        float X[16];
#pragma unroll
        for (int o = 0; o < 16; o++) {
            float x = s_stage[768 + o];
#pragma unroll
            for (int d = 0; d < 8; d++) x = fmaf(line[d], s_stage[o * 8 + d], x);
            X[o] = fmaxf(x, 0.f);
        }
        int o0 = part * 5;
#pragma unroll
        for (int oo = 0; oo < 5; oo++) {
            int o = o0 + oo;
            float a = 0.25f * s_stage[800 + o];
            float bb = a;
#pragma unroll
            for (int c = 0; c < 16; c++) {
                a  = fmaf(X[c], s_stage[128 + o * 32 + c], a);
                bb = fmaf(X[c], s_stage[128 + o * 32 + 16 + c], bb);
            }
            ws[WS_YA + key * 20 + o] = a;
            ws[WS_YB + key * 20 + o] = bb;
        }
    }

    // WCM (w_comb with relu(yc) folded)
    for (int idx = tid; idx < 800; idx += 256) {
        int m = idx / 400;
        int r = idx - m * 400;
        int q = r / 20;
        int o = r - q * 20;
        float yc = b_const[o];
#pragma unroll
        for (int k = 0; k < 4; k++)
            yc = fmaf(w_const[o * 4 + k], emb_const[m * 4 + k], yc);
        ws[WS_WCM + idx] = w_comb[q * 20 + o] * fmaxf(yc, 0.f);
    }
    if (tid < 20) { ws[WS_BCOMB + tid] = b_comb[tid]; ws[WS_WFIN + tid] = w_final[tid]; }
    if (tid == 0) ws[WS_BFIN] = b_final[0];
}

// ---------------- main ------------------------------------------------------
// 256-thread blocks (4 waves), grid = 8 * B/128. Block = (phase i, 128-bp chunk).
// Waves: w0=(jgrp A, bp 0..63) w1=(B, bp 0..63) w2=(A, bp 64..127) w3=(B, bp 64..127).
// Group A handles j=0..3 (xf[4][20]), group B j=4..6 (xf[3][20]); partials
// combined through LDS. W matrices read from global ws with uniform indices
// (-> scalar s_load, no LDS); only the 60-key Y tables live in LDS.
__global__ __launch_bounds__(256, 4) void frap_main(
    const float* __restrict__ feat, const int* __restrict__ cmask,
    const float* __restrict__ ws, float* __restrict__ out, int B)
{
    __shared__ __align__(16) float s_y[2400];   // [0,1200)=YA  [1200,2400)=YB
    __shared__ float s_part[256];

    const int tid = threadIdx.x;
    for (int k = tid; k < 600; k += 256)
        ((float4*)s_y)[k] = ((const float4*)(ws + WS_YA))[k];

    const int i = blockIdx.x & 7;
    const int chunk = blockIdx.x >> 3;
    unsigned mrow = 0;
#pragma unroll
    for (int j = 0; j < 7; j++) mrow |= ((unsigned)cmask[i * 7 + j] & 1u) << j;
    __syncthreads();

    const int lane = tid & 63;
    const int wv = tid >> 6;          // 0..3
    const int grp = wv & 1;           // 0: j=0..3, 1: j=4..6
    const int sub = wv >> 1;
    const int bp = (chunk << 7) + (sub << 6) + lane;
    const bool valid = bp < B;
    const int bpc = valid ? bp : 0;

    const float* s_ya = s_y;
    const float* s_yb = s_y + 1200;
    const unsigned Bu = (unsigned)B;
    const unsigned L0T = 0x64204051u, L1T = 0x75316273u;

    const int jbase = grp ? 4 : 0;
    unsigned g = 56u * (unsigned)bpc + 7u * (unsigned)i + (unsigned)jbase;
    unsigned p = g / Bu;
    unsigned b = g - p * Bu;
    unsigned pi = p / 7u;
    unsigned c7 = p - pi * 7u;
    unsigned pj = c7 + (c7 >= pi ? 1u : 0u);
    int la0 = (L0T >> (pi * 4)) & 15, la1 = (L1T >> (pi * 4)) & 15;
    int lb0 = (L0T >> (pj * 4)) & 15, lb1 = (L1T >> (pj * 4)) & 15;

#define BUILD_XF(dst)                                                          \
    do {                                                                       \
        if (b >= Bu) {                                                         \
            b -= Bu; p++;                                                      \
            pi = p / 7u; c7 = p - pi * 7u;                                     \
            pj = c7 + (c7 >= pi ? 1u : 0u);                                    \
            la0 = (L0T >> (pi * 4)) & 15; la1 = (L1T >> (pi * 4)) & 15;        \
            lb0 = (L0T >> (pj * 4)) & 15; lb1 = (L1T >> (pj * 4)) & 15;        \
        }                                                                      \
        const float* row = feat + (size_t)b * 16;                              \
        float bA0 = row[la0], vA0 = row[8 + la0];                              \
        float bA1 = row[la1], vA1 = row[8 + la1];                              \
        float bB0 = row[lb0], vB0 = row[8 + lb0];                              \
        float bB1 = row[lb1], vB1 = row[8 + lb1];                              \
        int kA0 = (int)fmaf(vA0, 2.f, bA0);                                    \
        int kA1 = (int)fmaf(vA1, 2.f, bA1);                                    \
        int kB0 = (int)fmaf(vB0, 2.f, bB0);                                    \
        int kB1 = (int)fmaf(vB1, 2.f, bB1);                                    \
        kA0 = min(59, max(0, kA0)); kA1 = min(59, max(0, kA1));                \
        kB0 = min(59, max(0, kB0)); kB1 = min(59, max(0, kB1));                \
        const float4* A0 = (const float4*)(s_ya + kA0 * 20);                   \
        const float4* A1 = (const float4*)(s_ya + kA1 * 20);                   \
        const float4* B0 = (const float4*)(s_yb + kB0 * 20);                   \
        const float4* B1 = (const float4*)(s_yb + kB1 * 20);                   \
        _Pragma("unroll")                                                      \
        for (int r = 0; r < 5; r++) {                                          \
            float4 a0 = A0[r], a1 = A1[r], c0 = B0[r], c1 = B1[r];             \
            dst[4 * r + 0] = fmaxf(a0.x + a1.x + c0.x + c1.x, 0.f);            \
            dst[4 * r + 1] = fmaxf(a0.y + a1.y + c0.y + c1.y, 0.f);            \
            dst[4 * r + 2] = fmaxf(a0.z + a1.z + c0.z + c1.z, 0.f);            \
            dst[4 * r + 3] = fmaxf(a0.w + a1.w + c0.w + c1.w, 0.f);            \
        }                                                                      \
        b++;                                                                   \
    } while (0)

// data param named Xv so it can't collide with .x/.y/.z/.w member tokens
#define DOT20(h, w0, w1, w2, w3, w4, Xv)                                       \
    h = fmaf(w0.x, Xv[0],  h); h = fmaf(w0.y, Xv[1],  h);                      \
    h = fmaf(w0.z, Xv[2],  h); h = fmaf(w0.w, Xv[3],  h);                      \
    h = fmaf(w1.x, Xv[4],  h); h = fmaf(w1.y, Xv[5],  h);                      \
    h = fmaf(w1.z, Xv[6],  h); h = fmaf(w1.w, Xv[7],  h);                      \
    h = fmaf(w2.x, Xv[8],  h); h = fmaf(w2.y, Xv[9],  h);                      \
    h = fmaf(w2.z, Xv[10], h); h = fmaf(w2.w, Xv[11], h);                      \
    h = fmaf(w3.x, Xv[12], h); h = fmaf(w3.y, Xv[13], h);                      \
    h = fmaf(w3.z, Xv[14], h); h = fmaf(w3.w, Xv[15], h);                      \
    h = fmaf(w4.x, Xv[16], h); h = fmaf(w4.y, Xv[17], h);                      \
    h = fmaf(w4.z, Xv[18], h); h = fmaf(w4.w, Xv[19], h)

    const float bfin = ws[WS_BFIN];
    float total = 0.f;

    if (grp == 0) {                       // ---- j = 0..3 ----
        float xf[4][20];
#pragma unroll
        for (int j = 0; j < 4; j++) BUILD_XF(xf[j]);
        float acc[4] = {0.f, 0.f, 0.f, 0.f};
        for (int q = 0; q < 20; q++) {
            const float4* w0p = (const float4*)(ws + WS_WCM + q * 20);
            const float4* w1p = (const float4*)(ws + WS_WCM + 400 + q * 20);
            float4 u0 = w0p[0], u1 = w0p[1], u2 = w0p[2], u3 = w0p[3], u4 = w0p[4];
            float4 v0 = w1p[0], v1 = w1p[1], v2 = w1p[2], v3 = w1p[3], v4 = w1p[4];
            float bq = ws[WS_BCOMB + q], wq = ws[WS_WFIN + q];
#pragma unroll
            for (int jj = 0; jj < 4; jj++) {
                float h = bq;
                if (mrow & (1u << jj)) { DOT20(h, v0, v1, v2, v3, v4, xf[jj]); }
                else                   { DOT20(h, u0, u1, u2, u3, u4, xf[jj]); }
                acc[jj] = fmaf(wq, fmaxf(h, 0.f), acc[jj]);
            }
        }
#pragma unroll
        for (int jj = 0; jj < 4; jj++) total += fmaxf(acc[jj] + bfin, 0.f);
    } else {                              // ---- j = 4..6 ----
        float xf[3][20];
#pragma unroll
        for (int j = 0; j < 3; j++) BUILD_XF(xf[j]);
        float acc[3] = {0.f, 0.f, 0.f};
        for (int q = 0; q < 20; q++) {
            const float4* w0p = (const float4*)(ws + WS_WCM + q * 20);
            const float4* w1p = (const float4*)(ws + WS_WCM + 400 + q * 20);
            float4 u0 = w0p[0], u1 = w0p[1], u2 = w0p[2], u3 = w0p[3], u4 = w0p[4];
            float4 v0 = w1p[0], v1 = w1p[1], v2 = w1p[2], v3 = w1p[3], v4 = w1p[4];
            float bq = ws[WS_BCOMB + q], wq = ws[WS_WFIN + q];
#pragma unroll
            for (int jj = 0; jj < 3; jj++) {
                float h = bq;
                if (mrow & (1u << (4 + jj))) { DOT20(h, v0, v1, v2, v3, v4, xf[jj]); }
                else                         { DOT20(h, u0, u1, u2, u3, u4, xf[jj]); }
                acc[jj] = fmaf(wq, fmaxf(h, 0.f), acc[jj]);
            }
        }
#pragma unroll
        for (int jj = 0; jj < 3; jj++) total += fmaxf(acc[jj] + bfin, 0.f);
    }
#undef BUILD_XF
#undef DOT20

    s_part[tid] = total;
    __syncthreads();
    if (grp == 0 && valid)
        out[(size_t)bp * 8 + i] = total + s_part[tid + 64];
}

extern "C" void kernel_launch(void* const* d_in, const int* in_sizes, int n_in,
                              void* d_out, int out_size, void* d_ws, size_t ws_size,
                              hipStream_t stream) {
    const float* feat      = (const float*)d_in[0];
    const float* emb_phase = (const float*)d_in[1];
    const float* w_veh     = (const float*)d_in[2];
    const float* b_veh     = (const float*)d_in[3];
    const float* w_line    = (const float*)d_in[4];
    const float* b_line    = (const float*)d_in[5];
    const float* emb_const = (const float*)d_in[6];
    const float* w_feat    = (const float*)d_in[7];
    const float* b_feat    = (const float*)d_in[8];
    const float* w_const   = (const float*)d_in[9];
    const float* b_const   = (const float*)d_in[10];
    const float* w_comb    = (const float*)d_in[11];
    const float* b_comb    = (const float*)d_in[12];
    const float* w_final   = (const float*)d_in[13];
    const float* b_final   = (const float*)d_in[14];
    const int*   cmask     = (const int*)d_in[15];

    int B = in_sizes[0] / 16;                 // 16384
    float* ws = (float*)d_ws;

    frap_setup<<<1, 256, 0, stream>>>(emb_phase, w_veh, b_veh, w_line, b_line,
                                      emb_const, w_feat, b_feat, w_const,
                                      b_const, w_comb, b_comb, w_final,
                                      b_final, ws);
    int blocks = 8 * ((B + 127) / 128);       // 1024
    frap_main<<<blocks, 256, 0, stream>>>(feat, cmask, ws, (float*)d_out, B);
}

// Round 9
// 113.218 us; speedup vs baseline: 1.3241x; 1.3241x over previous
//
#include <hip/hip_runtime.h>
#include <hip/hip_bf16.h>

__device__ __forceinline__ float sigm(float x) { return 1.0f / (1.0f + __expf(-x)); }

// Workspace float layout (all written by frap_setup every launch):
#define WS_WCM   0      // [2][20][20] = 800   w_comb * relu(yc) per mask value
#define WS_YA    800    // [60][20]            w_feat[:, :16] . X[key]  (+ b_feat/4)
#define WS_YB    2000   // [60][20]            w_feat[:, 16:] . X[key]  (+ b_feat/4)
#define WS_BCOMB 3200   // 20
#define WS_WFIN  3220   // 20
#define WS_BFIN  3240   // 1

// ---------------- setup: tiny, 1 block. Computes all derived tables. --------
__global__ __launch_bounds__(256) void frap_setup(
    const float* __restrict__ emb_phase, const float* __restrict__ w_veh,
    const float* __restrict__ b_veh,     const float* __restrict__ w_line,
    const float* __restrict__ b_line,    const float* __restrict__ emb_const,
    const float* __restrict__ w_feat,    const float* __restrict__ b_feat,
    const float* __restrict__ w_const,   const float* __restrict__ b_const,
    const float* __restrict__ w_comb,    const float* __restrict__ b_comb,
    const float* __restrict__ w_final,   const float* __restrict__ b_final,
    float* __restrict__ ws)
{
    __shared__ float s_stage[820];   // [0,128)=w_line [128,768)=w_feat [768,784)=b_line
                                     // [784,788)=w_veh [788,792)=b_veh [792,800)=emb_phase [800,820)=b_feat
    const int tid = threadIdx.x;
    for (int k = tid; k < 128; k += 256) s_stage[k] = w_line[k];
    for (int k = tid; k < 640; k += 256) s_stage[128 + k] = w_feat[k];
    if (tid < 16)                s_stage[768 + tid] = b_line[tid];
    if (tid < 4)                 s_stage[784 + tid] = w_veh[tid];
    if (tid >= 4 && tid < 8)     s_stage[784 + tid] = b_veh[tid - 4];
    if (tid >= 8 && tid < 16)    s_stage[784 + tid] = emb_phase[tid - 8];
    if (tid >= 16 && tid < 36)   s_stage[784 + tid] = b_feat[tid - 16];
    __syncthreads();

    // YA/YB: 240 threads, 4 per key (5 outputs each)
    if (tid < 240) {
        int key = tid >> 2, part = tid & 3;
        int veh = key >> 1, pb = key & 1;
        float vf = (float)veh;
        float line[8];
#pragma unroll
        for (int k = 0; k < 4; k++) line[k] = sigm(fmaf(vf, s_stage[784 + k], s_stage[788 + k]));
#pragma unroll
        for (int k = 0; k < 4; k++) line[4 + k] = sigm(s_stage[792 + pb * 4 + k]);
        float X[16];
#pragma unroll
        for (int o = 0; o < 16; o++) {
            float x = s_stage[768 + o];
#pragma unroll
            for (int d = 0; d < 8; d++) x = fmaf(line[d], s_stage[o * 8 + d], x);
            X[o] = fmaxf(x, 0.f);
        }
        int o0 = part * 5;
#pragma unroll
        for (int oo = 0; oo < 5; oo++) {
            int o = o0 + oo;
            float a = 0.25f * s_stage[800 + o];
            float bb = a;
#pragma unroll
            for (int c = 0; c < 16; c++) {
                a  = fmaf(X[c], s_stage[128 + o * 32 + c], a);
                bb = fmaf(X[c], s_stage[128 + o * 32 + 16 + c], bb);
            }
            ws[WS_YA + key * 20 + o] = a;
            ws[WS_YB + key * 20 + o] = bb;
        }
    }

    // WCM (w_comb with relu(yc) folded)
    for (int idx = tid; idx < 800; idx += 256) {
        int m = idx / 400;
        int r = idx - m * 400;
        int q = r / 20;
        int o = r - q * 20;
        float yc = b_const[o];
#pragma unroll
        for (int k = 0; k < 4; k++)
            yc = fmaf(w_const[o * 4 + k], emb_const[m * 4 + k], yc);
        ws[WS_WCM + idx] = w_comb[q * 20 + o] * fmaxf(yc, 0.f);
    }
    if (tid < 20) { ws[WS_BCOMB + tid] = b_comb[tid]; ws[WS_WFIN + tid] = w_final[tid]; }
    if (tid == 0) ws[WS_BFIN] = b_final[0];
}

// ---------------- main ------------------------------------------------------
// 448-thread blocks = 7 waves. Block = (phase i, 64-bp chunk); wave jw handles
// competitor j=jw for all 64 bp. One j per thread -> live set ~50 VGPRs (xf[20]
// + staged table rows), fits the 64-VGPR bucket with NO spill at any occupancy.
// Mask bit is (i,jw)-uniform -> scalar W-base select; q-loop reads one 20-float
// W row per iter via uniform s_load. Only the 60-key Y tables live in LDS.
// Partials combined via s_part with j-sequential order (matches reference).
__global__ __launch_bounds__(448, 4) void frap_main(
    const float* __restrict__ feat, const int* __restrict__ cmask,
    const float* __restrict__ ws, float* __restrict__ out, int B)
{
    __shared__ __align__(16) float s_y[2400];   // [0,1200)=YA  [1200,2400)=YB
    __shared__ float s_part[448];

    const int tid = threadIdx.x;
    for (int k = tid; k < 600; k += 448)
        ((float4*)s_y)[k] = ((const float4*)(ws + WS_YA))[k];

    const int i = blockIdx.x & 7;              // phase (uniform per block)
    const int chunk = blockIdx.x >> 3;
    const int lane = tid & 63;
    const int jw = __builtin_amdgcn_readfirstlane(tid >> 6);   // 0..6, scalar
    const int bp = (chunk << 6) + lane;
    const bool valid = bp < B;
    const int bpc = valid ? bp : 0;

    // mask bit for (i, jw): scalar -> scalar W base
    const int mbit = __builtin_amdgcn_readfirstlane(cmask[i * 7 + jw]) & 1;
    const float* wbase = ws + WS_WCM + (mbit ? 400 : 0);
    __syncthreads();

    // source (pair p, batch b) for flat index g = 56*bp + 7*i + jw
    const unsigned Bu = (unsigned)B;
    unsigned g = 56u * (unsigned)bpc + 7u * (unsigned)i + (unsigned)jw;
    unsigned p = g / Bu;
    unsigned b = g - p * Bu;
    unsigned pi = p / 7u;
    unsigned c7 = p - pi * 7u;
    unsigned pj = c7 + (c7 >= pi ? 1u : 0u);

    const unsigned L0T = 0x64204051u, L1T = 0x75316273u;  // PHASE_LANES nibbles
    int la0 = (L0T >> (pi * 4)) & 15, la1 = (L1T >> (pi * 4)) & 15;
    int lb0 = (L0T >> (pj * 4)) & 15, lb1 = (L1T >> (pj * 4)) & 15;

    const float* row = feat + (size_t)b * 16;
    float bA0 = row[la0], vA0 = row[8 + la0];
    float bA1 = row[la1], vA1 = row[8 + la1];
    float bB0 = row[lb0], vB0 = row[8 + lb0];
    float bB1 = row[lb1], vB1 = row[8 + lb1];
    int kA0 = min(59, max(0, (int)fmaf(vA0, 2.f, bA0)));
    int kA1 = min(59, max(0, (int)fmaf(vA1, 2.f, bA1)));
    int kB0 = min(59, max(0, (int)fmaf(vB0, 2.f, bB0)));
    int kB1 = min(59, max(0, (int)fmaf(vB1, 2.f, bB1)));

    const float4* A0 = (const float4*)(s_y + kA0 * 20);
    const float4* A1 = (const float4*)(s_y + kA1 * 20);
    const float4* B0 = (const float4*)(s_y + 1200 + kB0 * 20);
    const float4* B1 = (const float4*)(s_y + 1200 + kB1 * 20);

    float xf[20];
#pragma unroll
    for (int r = 0; r < 5; r++) {
        float4 a0 = A0[r], a1 = A1[r], c0 = B0[r], c1 = B1[r];
        xf[4 * r + 0] = fmaxf(a0.x + a1.x + c0.x + c1.x, 0.f);
        xf[4 * r + 1] = fmaxf(a0.y + a1.y + c0.y + c1.y, 0.f);
        xf[4 * r + 2] = fmaxf(a0.z + a1.z + c0.z + c1.z, 0.f);
        xf[4 * r + 3] = fmaxf(a0.w + a1.w + c0.w + c1.w, 0.f);
    }

    float acc = 0.f;
    for (int q = 0; q < 20; q++) {
        const float4* wr = (const float4*)(wbase + q * 20);   // uniform -> s_load
        float4 w0 = wr[0], w1 = wr[1], w2 = wr[2], w3 = wr[3], w4 = wr[4];
        float h = ws[WS_BCOMB + q];
        h = fmaf(w0.x, xf[0],  h); h = fmaf(w0.y, xf[1],  h);
        h = fmaf(w0.z, xf[2],  h); h = fmaf(w0.w, xf[3],  h);
        h = fmaf(w1.x, xf[4],  h); h = fmaf(w1.y, xf[5],  h);
        h = fmaf(w1.z, xf[6],  h); h = fmaf(w1.w, xf[7],  h);
        h = fmaf(w2.x, xf[8],  h); h = fmaf(w2.y, xf[9],  h);
        h = fmaf(w2.z, xf[10], h); h = fmaf(w2.w, xf[11], h);
        h = fmaf(w3.x, xf[12], h); h = fmaf(w3.y, xf[13], h);
        h = fmaf(w3.z, xf[14], h); h = fmaf(w3.w, xf[15], h);
        h = fmaf(w4.x, xf[16], h); h = fmaf(w4.y, xf[17], h);
        h = fmaf(w4.z, xf[18], h); h = fmaf(w4.w, xf[19], h);
        acc = fmaf(ws[WS_WFIN + q], fmaxf(h, 0.f), acc);
    }
    float val = fmaxf(acc + ws[WS_BFIN], 0.f);

    s_part[tid] = val;
    __syncthreads();
    if (jw == 0 && valid) {
        float total = val;                     // j = 0
#pragma unroll
        for (int w = 1; w < 7; w++)            // j = 1..6 in order
            total += s_part[lane + (w << 6)];
        out[(size_t)bp * 8 + i] = total;
    }
}

extern "C" void kernel_launch(void* const* d_in, const int* in_sizes, int n_in,
                              void* d_out, int out_size, void* d_ws, size_t ws_size,
                              hipStream_t stream) {
    const float* feat      = (const float*)d_in[0];
    const float* emb_phase = (const float*)d_in[1];
    const float* w_veh     = (const float*)d_in[2];
    const float* b_veh     = (const float*)d_in[3];
    const float* w_line    = (const float*)d_in[4];
    const float* b_line    = (const float*)d_in[5];
    const float* emb_const = (const float*)d_in[6];
    const float* w_feat    = (const float*)d_in[7];
    const float* b_feat    = (const float*)d_in[8];
    const float* w_const   = (const float*)d_in[9];
    const float* b_const   = (const float*)d_in[10];
    const float* w_comb    = (const float*)d_in[11];
    const float* b_comb    = (const float*)d_in[12];
    const float* w_final   = (const float*)d_in[13];
    const float* b_final   = (const float*)d_in[14];
    const int*   cmask     = (const int*)d_in[15];

    int B = in_sizes[0] / 16;                 // 16384
    float* ws = (float*)d_ws;

    frap_setup<<<1, 256, 0, stream>>>(emb_phase, w_veh, b_veh, w_line, b_line,
                                      emb_const, w_feat, b_feat, w_const,
                                      b_const, w_comb, b_comb, w_final,
                                      b_final, ws);
    int blocks = 8 * ((B + 63) / 64);         // 2048
    frap_main<<<blocks, 448, 0, stream>>>(feat, cmask, ws, (float*)d_out, B);
}